// Round 8
// baseline (253.785 us; speedup 1.0000x reference)
//
#include <hip/hip_runtime.h>
#include <hip/hip_bf16.h>
#include <hip/hip_fp8.h>

// TextualContrastiveLoss: B=4096, D=1024, NUM_CLASSES=100, T=0.5
//   z = l2norm(emb); reps = [z_i; z_j] (8192x1024)
//   sim = reps @ reps^T; e = exp(sim/T) with diag excluded
//   loss = mean_n( log(sum_m e) - log(sum_{m: lab match} e) )
//
// R1..R2: 128x128 LDS GEMM + xor swizzle: 366us, latency-bound.
// R3: upper-tri symmetry + dual scatter: 171us. R4: 256-tiles regressed.
// R5: no-LDS regressed (16-line scatter/instr). R6: dbuf bf16: 158us —
//     __syncthreads forces vmcnt(0), drains expose L3/HBM latency.
// R7: fp8 BK=128: 136us; b64 frag reads pay +4cyc/read bank conflicts.
// R8: BARRIER-FREE wave-private pipeline. 64-thread blocks, 64x64 tile,
//     each wave stages its own A/B rows to private LDS (2-deep, 32KB),
//     syncs ONLY on its own s_waitcnt vmcnt(N) -> loads in flight a full
//     compute phase; no cross-wave coupling at all. K-remap: quad owns
//     cols [32q,+32), ks indexes 8B chunks -> paired-ks ds_read_b128
//     (R6's proven 0-conflict geometry). 5 blocks/CU (LDS-bound).

#define BHALF 4096
#define N2 8192
#define DK 1024               // elements per row; fp8 => 1024 B
#define TS 64                 // tile size
#define BKB 128               // K bytes staged per kt (8 kt total)
#define NT 128                // 8192/64 tile rows
#define NBLK 8256             // NT*(NT+1)/2 upper-tri tiles

typedef __attribute__((ext_vector_type(4))) float f32x4;
typedef __attribute__((ext_vector_type(2))) long v2l;
typedef unsigned char u8;

// exp(s/0.5) = exp2(s * 2*log2(e))
#define EXP_SCALE 2.8853900817779268f

// wait on own vector-mem counter only; memory clobber pins ordering
#define WAITVM(n) asm volatile("s_waitcnt vmcnt(" #n ")" ::: "memory")
#define CFENCE()  asm volatile("" ::: "memory")

__global__ __launch_bounds__(256) void normalize_kernel(
    const float* __restrict__ emb_i, const float* __restrict__ emb_j,
    u8* __restrict__ reps, float* __restrict__ nomden,
    float* __restrict__ out) {
    int r = blockIdx.x;           // 0..8191
    int t = threadIdx.x;          // 0..255, one float4 each
    int idx = r * 256 + t;
    if (idx < 2 * N2) nomden[idx] = 0.0f;     // fused zero of nom+den
    if (idx == 0) out[0] = 0.0f;
    const float* src = (r < BHALF) ? (emb_i + (size_t)r * DK)
                                   : (emb_j + (size_t)(r - BHALF) * DK);
    float4 v = ((const float4*)src)[t];
    float s = v.x * v.x + v.y * v.y + v.z * v.z + v.w * v.w;
#pragma unroll
    for (int m = 1; m <= 32; m <<= 1) s += __shfl_xor(s, m, 64);
    __shared__ float red[4];
    if ((t & 63) == 0) red[t >> 6] = s;
    __syncthreads();
    float tot = red[0] + red[1] + red[2] + red[3];
    float scale = 1.0f / fmaxf(sqrtf(tot), 1e-12f);
    __hip_fp8_e4m3 q0(v.x * scale), q1(v.y * scale),
                   q2(v.z * scale), q3(v.w * scale);
    uchar4 o = make_uchar4(q0.__x, q1.__x, q2.__x, q3.__x);
    ((uchar4*)(reps + (size_t)r * DK))[t] = o;
}

static __device__ __forceinline__ int tri_cum(int b) {
    return b * (2 * NT - b + 1) / 2;   // tiles before row b
}

__global__ __launch_bounds__(64) void gemm_loss_kernel(
    const u8* __restrict__ reps, const int* __restrict__ labels,
    float* __restrict__ nom, float* __restrict__ den) {
    // wave-private LDS: [buf][A/B][64 rows x 128 B] = 32 KB
    __shared__ __align__(16) u8 lds[2][2][TS * BKB];

    // upper-tri decode via sqrt + fixup
    int rem = blockIdx.x;
    float ff = 2.0f * NT + 1.0f;
    int bi = (int)(0.5f * (ff - sqrtf(ff * ff - 8.0f * (float)rem)));
    if (bi < 0) bi = 0;
    if (bi > NT - 1) bi = NT - 1;
    while (tri_cum(bi + 1) <= rem) ++bi;
    while (tri_cum(bi) > rem) --bi;
    int bj = bi + (rem - tri_cum(bi));
    int rowBase = bi * TS;
    int colBase = bj * TS;

    int lane = threadIdx.x;       // 0..63
    int quad = lane >> 4;
    int l15 = lane & 15;

    f32x4 acc[4][4];
#pragma unroll
    for (int i = 0; i < 4; ++i)
#pragma unroll
        for (int j = 0; j < 4; ++j)
            acc[i][j] = (f32x4){0.f, 0.f, 0.f, 0.f};

    // staging: lane l -> slot (l>>3, l&7)@16B per 1KB chunk (8 rows);
    // fetches global 16B col-block (l&7)^(l>>3) to realize xor swizzle
    int srow = lane >> 3;
    int scb = (lane & 7) ^ srow;
    const u8* gA = reps + (size_t)(rowBase + srow) * DK + scb * 16;
    const u8* gB = reps + (size_t)(colBase + srow) * DK + scb * 16;

#define STAGE(buf, kt)                                                       \
    {                                                                        \
        _Pragma("unroll")                                                    \
        for (int c = 0; c < 8; ++c) {                                        \
            __builtin_amdgcn_global_load_lds(                                \
                (const __attribute__((address_space(1))) void*)              \
                    (gA + (size_t)c * 8 * DK + (kt) * BKB),                  \
                (__attribute__((address_space(3))) void*)                    \
                    &lds[buf][0][c * 1024], 16, 0, 0);                       \
            __builtin_amdgcn_global_load_lds(                                \
                (const __attribute__((address_space(1))) void*)              \
                    (gB + (size_t)c * 8 * DK + (kt) * BKB),                  \
                (__attribute__((address_space(3))) void*)                    \
                    &lds[buf][1][c * 1024], 16, 0, 0);                       \
        }                                                                    \
    }
    // K-remap: quad q owns global cols [32q,32q+32); pair p covers its
    // 16B block 2q+p = frags ks=2p (lo 8B) and ks=2p+1 (hi 8B). A and B
    // use the same mapping, so each MFMA consumes a consistent col set.
#define COMPUTE(buf)                                                         \
    {                                                                        \
        _Pragma("unroll")                                                    \
        for (int p = 0; p < 2; ++p) {                                        \
            v2l a2[4], b2[4];                                                \
            _Pragma("unroll")                                                \
            for (int i = 0; i < 4; ++i) {                                    \
                int r = i * 16 + l15;                                        \
                int blk = (2 * quad + p) ^ (r & 7);                          \
                a2[i] = *(const v2l*)&lds[buf][0][r * BKB + blk * 16];       \
                b2[i] = *(const v2l*)&lds[buf][1][r * BKB + blk * 16];       \
            }                                                                \
            _Pragma("unroll")                                                \
            for (int i = 0; i < 4; ++i)                                      \
                _Pragma("unroll")                                            \
                for (int j = 0; j < 4; ++j) {                                \
                    acc[i][j] = __builtin_amdgcn_mfma_f32_16x16x32_fp8_fp8(  \
                        a2[i][0], b2[j][0], acc[i][j], 0, 0, 0);             \
                    acc[i][j] = __builtin_amdgcn_mfma_f32_16x16x32_fp8_fp8(  \
                        a2[i][1], b2[j][1], acc[i][j], 0, 0, 0);             \
                }                                                            \
        }                                                                    \
    }

    STAGE(0, 0)
    STAGE(1, 1)
    for (int kt = 0; kt < 6; kt += 2) {
        WAITVM(16);               // buf0's 16 loads retired (buf1's in flight)
        COMPUTE(0)
        CFENCE();                 // keep restage after the ds_reads
        STAGE(0, kt + 2)
        WAITVM(16);
        COMPUTE(1)
        CFENCE();
        STAGE(1, kt + 3)
    }
    WAITVM(16);
    COMPUTE(0)                    // kt = 6
    WAITVM(0);
    COMPUTE(1)                    // kt = 7
#undef STAGE
#undef COMPUTE

    // Epilogue. C/D layout (m89-verified, dtype-independent):
    //   col = lane&15, row = quad*4 + reg.
    // Strict-upper masking (gc<=gr -> 0) makes every tile emit exactly the
    // unordered pairs it owns; dual row/col scatter is unconditional.
    int lc[4], gcol[4];
#pragma unroll
    for (int j = 0; j < 4; ++j) {
        gcol[j] = colBase + j * 16 + l15;
        lc[j] = labels[gcol[j] & (BHALF - 1)];   // 16KB table, cache-hot
    }
    float colD[4] = {0.f, 0.f, 0.f, 0.f};
    float colN[4] = {0.f, 0.f, 0.f, 0.f};
#pragma unroll
    for (int i = 0; i < 4; ++i) {
#pragma unroll
        for (int reg = 0; reg < 4; ++reg) {
            int grow = rowBase + i * 16 + quad * 4 + reg;
            int labr = labels[grow & (BHALF - 1)];
            float rD = 0.f, rN = 0.f;
#pragma unroll
            for (int j = 0; j < 4; ++j) {
                float e = exp2f(acc[i][j][reg] * EXP_SCALE);
                if (gcol[j] <= grow) e = 0.f;   // lower tri + diag excluded
                bool m = (lc[j] == labr);
                rD += e; if (m) rN += e;
                colD[j] += e; if (m) colN[j] += e;
            }
            // row sums: reduce across the 16 column-lanes of this quad
#pragma unroll
            for (int msk = 1; msk <= 8; msk <<= 1) {
                rD += __shfl_xor(rD, msk, 64);
                rN += __shfl_xor(rN, msk, 64);
            }
            if (l15 == 0) {
                atomicAdd(&den[grow], rD);
                atomicAdd(&nom[grow], rN);
            }
        }
    }
    // symmetric counterpart: column sums scattered as row sums of (c,r)
#pragma unroll
    for (int j = 0; j < 4; ++j) {
        float cd = colD[j], cn = colN[j];
        cd += __shfl_xor(cd, 16, 64); cn += __shfl_xor(cn, 16, 64);
        cd += __shfl_xor(cd, 32, 64); cn += __shfl_xor(cn, 32, 64);
        if (quad == 0) {
            atomicAdd(&den[gcol[j]], cd);
            atomicAdd(&nom[gcol[j]], cn);
        }
    }
}

__global__ __launch_bounds__(256) void finalize_kernel(
    const float* __restrict__ nom, const float* __restrict__ den,
    float* __restrict__ out) {
    int idx = blockIdx.x * 256 + threadIdx.x;   // 32 blocks x 256
    int t = threadIdx.x;
    float s = 0.f;
    if (idx < N2) s = logf(den[idx]) - logf(nom[idx]);   // -log(nom/den)
#pragma unroll
    for (int m = 1; m <= 32; m <<= 1) s += __shfl_xor(s, m, 64);
    __shared__ float red[4];
    if ((t & 63) == 0) red[t >> 6] = s;
    __syncthreads();
    if (t == 0)
        atomicAdd(out, (red[0] + red[1] + red[2] + red[3]) / (float)N2);
}

extern "C" void kernel_launch(void* const* d_in, const int* in_sizes, int n_in,
                              void* d_out, int out_size, void* d_ws, size_t ws_size,
                              hipStream_t stream) {
    const float* emb_i = (const float*)d_in[0];
    const float* emb_j = (const float*)d_in[1];
    const int* labels  = (const int*)d_in[2];
    float* out = (float*)d_out;

    char* ws = (char*)d_ws;
    u8* reps   = (u8*)ws;                                   // 8192*1024 = 8 MB
    float* nom = (float*)(ws + (size_t)N2 * DK);            // 32 KB
    float* den = nom + N2;                                  // 32 KB

    normalize_kernel<<<N2, 256, 0, stream>>>(emb_i, emb_j, reps, nom, out);
    gemm_loss_kernel<<<NBLK, 64, 0, stream>>>(reps, labels, nom, den);
    finalize_kernel<<<(N2 + 255) / 256, 256, 0, stream>>>(nom, den, out);
}

// Round 9
// 175.851 us; speedup vs baseline: 1.4432x; 1.4432x over previous
//
#include <hip/hip_runtime.h>
#include <hip/hip_bf16.h>
#include <hip/hip_fp8.h>

// TextualContrastiveLoss: B=4096, D=1024, NUM_CLASSES=100, T=0.5
//   z = l2norm(emb); reps = [z_i; z_j] (8192x1024)
//   sim = reps @ reps^T; e = exp(sim/T) with diag excluded
//   loss = mean_n( log(sum_m e) - log(sum_{m: lab match} e) )
//
// R1..R2: 128x128 LDS GEMM + xor swizzle: 366us. R3: +symmetry: 171us.
// R4: 256-tiles regressed. R5: no-LDS regressed. R6: dbuf bf16 158us.
// R7: fp8 BKB=128 dbuf: 136us — all pipes ~20-25%, per-wave chains ~75%
//     stalled, only 2 blocks/CU (64KB LDS) -> no TLP to fill the holes.
// R8: wave-private barrier-free: REGRESSED 182us (5 waves/CU, 2x traffic).
// R9: R7 shape with BKB=64 -> LDS 32KB -> __launch_bounds__(256,4) ->
//     4 blocks/CU = 16 waves/CU (2x R7's TLP). Frag reads become one
//     ds_read_b128 per frag per kt (quad q owns k-chunk [16q,+16), lo/hi
//     8B feed 2 MFMAs); 4-block xor swizzle -> worst 2-way (free, m136).

#define BHALF 4096
#define N2 8192
#define DK 1024               // elements per row; fp8 => 1024 B
#define TILE 128
#define BKB 64                // K bytes staged per kt (16 kt total)
#define NTILE 64              // 8192/128
#define NBLK 2080             // 64*65/2 upper-tri tiles

typedef __attribute__((ext_vector_type(4))) float f32x4;
typedef __attribute__((ext_vector_type(2))) long v2l;
typedef unsigned char u8;

// exp(s/0.5) = exp2(s * 2*log2(e))
#define EXP_SCALE 2.8853900817779268f

__global__ __launch_bounds__(256) void normalize_kernel(
    const float* __restrict__ emb_i, const float* __restrict__ emb_j,
    u8* __restrict__ reps, float* __restrict__ nomden,
    float* __restrict__ out) {
    int r = blockIdx.x;           // 0..8191
    int t = threadIdx.x;          // 0..255, one float4 each
    int idx = r * 256 + t;
    if (idx < 2 * N2) nomden[idx] = 0.0f;     // fused zero of nom+den
    if (idx == 0) out[0] = 0.0f;
    const float* src = (r < BHALF) ? (emb_i + (size_t)r * DK)
                                   : (emb_j + (size_t)(r - BHALF) * DK);
    float4 v = ((const float4*)src)[t];
    float s = v.x * v.x + v.y * v.y + v.z * v.z + v.w * v.w;
#pragma unroll
    for (int m = 1; m <= 32; m <<= 1) s += __shfl_xor(s, m, 64);
    __shared__ float red[4];
    if ((t & 63) == 0) red[t >> 6] = s;
    __syncthreads();
    float tot = red[0] + red[1] + red[2] + red[3];
    float scale = 1.0f / fmaxf(sqrtf(tot), 1e-12f);
    __hip_fp8_e4m3 q0(v.x * scale), q1(v.y * scale),
                   q2(v.z * scale), q3(v.w * scale);
    uchar4 o = make_uchar4(q0.__x, q1.__x, q2.__x, q3.__x);
    ((uchar4*)(reps + (size_t)r * DK))[t] = o;
}

__global__ __launch_bounds__(256, 4) void gemm_loss_kernel(
    const u8* __restrict__ reps, const int* __restrict__ labels,
    float* __restrict__ nom, float* __restrict__ den) {
    // Double-buffered fp8 tiles: 2 x (A 8KB + B 8KB) = 32 KB.
    // Rows are 64 B = 4 x 16B col-blocks. XOR swizzle over 4 blocks:
    // LDS slot (row, b_lds) holds global col-block b_lds ^ (row&3).
    __shared__ __align__(16) u8 A_s[2][TILE * BKB];
    __shared__ __align__(16) u8 B_s[2][TILE * BKB];

    // upper-triangle decode: row-major over bi<=bj
    int rem = blockIdx.x;
    int bi = 0;
    while (rem >= NTILE - bi) { rem -= NTILE - bi; ++bi; }
    int bj = bi + rem;
    int rowBase = bi * TILE;
    int colBase = bj * TILE;

    int tid = threadIdx.x;
    int w = tid >> 6;             // wave 0..3 -> 2x2 of 64x64 subtiles
    int lane = tid & 63;
    int wm = w >> 1, wn = w & 1;
    int quad = lane >> 4;
    int l15 = lane & 15;

    f32x4 acc[4][4];
#pragma unroll
    for (int i = 0; i < 4; ++i)
#pragma unroll
        for (int j = 0; j < 4; ++j)
            acc[i][j] = (f32x4){0.f, 0.f, 0.f, 0.f};

    // staging: 1KB chunk = 16 rows x 64 B; lane l -> LDS (row 16c+(l>>2),
    // block l&3); fetches global block (l&3)^((l>>2)&3) for the swizzle
    int srow = lane >> 2;                       // 0..15 (row within chunk)
    int sbg = (lane & 3) ^ (srow & 3);          // swizzled global 16B block
    // wave w stages A-chunks {2w,2w+1} and B-chunks {2w,2w+1}
    const u8* gA = reps + (size_t)(rowBase + w * 32 + srow) * DK + sbg * 16;
    const u8* gB = reps + (size_t)(colBase + w * 32 + srow) * DK + sbg * 16;

    // fragment rows; read offsets: row r, block quad^(r&3), 16 B (b128)
    unsigned aOff[4], bOff[4];
#pragma unroll
    for (int i = 0; i < 4; ++i) {
        int ra = wm * 64 + i * 16 + l15;
        aOff[i] = ra * BKB + ((quad ^ (ra & 3)) << 4);
        int rb = wn * 64 + i * 16 + l15;
        bOff[i] = rb * BKB + ((quad ^ (rb & 3)) << 4);
    }

#define STAGE(buf, kt)                                                       \
    {                                                                        \
        _Pragma("unroll")                                                    \
        for (int c = 0; c < 2; ++c) {                                        \
            int chunk = 2 * w + c;                                           \
            __builtin_amdgcn_global_load_lds(                                \
                (const __attribute__((address_space(1))) void*)              \
                    (gA + (size_t)c * 16 * DK + (kt) * BKB),                 \
                (__attribute__((address_space(3))) void*)                    \
                    &A_s[buf][chunk * 1024], 16, 0, 0);                      \
            __builtin_amdgcn_global_load_lds(                                \
                (const __attribute__((address_space(1))) void*)              \
                    (gB + (size_t)c * 16 * DK + (kt) * BKB),                 \
                (__attribute__((address_space(3))) void*)                    \
                    &B_s[buf][chunk * 1024], 16, 0, 0);                      \
        }                                                                    \
    }
    // Per kt: quad q owns global k-chunk [16q,16q+16) of the 64 staged;
    // one b128 read per fragment; lo 8B -> MFMA s=0, hi 8B -> s=1.
#define COMPUTE(buf)                                                         \
    {                                                                        \
        v2l a2[4], b2[4];                                                    \
        _Pragma("unroll")                                                    \
        for (int i = 0; i < 4; ++i) {                                        \
            a2[i] = *(const v2l*)&A_s[buf][aOff[i]];                         \
            b2[i] = *(const v2l*)&B_s[buf][bOff[i]];                         \
        }                                                                    \
        _Pragma("unroll")                                                    \
        for (int i = 0; i < 4; ++i)                                          \
            _Pragma("unroll")                                                \
            for (int j = 0; j < 4; ++j) {                                    \
                acc[i][j] = __builtin_amdgcn_mfma_f32_16x16x32_fp8_fp8(      \
                    a2[i][0], b2[j][0], acc[i][j], 0, 0, 0);                 \
                acc[i][j] = __builtin_amdgcn_mfma_f32_16x16x32_fp8_fp8(      \
                    a2[i][1], b2[j][1], acc[i][j], 0, 0, 0);                 \
            }                                                                \
    }

    STAGE(0, 0)
    for (int kt = 0; kt < 14; kt += 2) {
        __syncthreads();          // drains buf0 loads (issued 1 phase ago)
        STAGE(1, kt + 1)
        COMPUTE(0)
        __syncthreads();
        STAGE(0, kt + 2)
        COMPUTE(1)
    }
    __syncthreads();
    STAGE(1, 15)
    COMPUTE(0)
    __syncthreads();
    COMPUTE(1)
#undef STAGE
#undef COMPUTE

    // Epilogue. C/D layout (m89-verified, dtype-independent):
    //   col = lane&15, row = quad*4 + reg.
    bool offd = (bi != bj);
    int lc[4], gcol[4];
#pragma unroll
    for (int j = 0; j < 4; ++j) {
        gcol[j] = colBase + wn * 64 + j * 16 + l15;
        lc[j] = labels[gcol[j] & (BHALF - 1)];   // 16KB table, cache-hot
    }
    float colD[4] = {0.f, 0.f, 0.f, 0.f};
    float colN[4] = {0.f, 0.f, 0.f, 0.f};
#pragma unroll
    for (int i = 0; i < 4; ++i) {
#pragma unroll
        for (int reg = 0; reg < 4; ++reg) {
            int grow = rowBase + wm * 64 + i * 16 + quad * 4 + reg;
            int labr = labels[grow & (BHALF - 1)];
            float rD = 0.f, rN = 0.f;
#pragma unroll
            for (int j = 0; j < 4; ++j) {
                float e = exp2f(acc[i][j][reg] * EXP_SCALE);
                if (grow == gcol[j]) e = 0.f;   // diag (only when bi==bj)
                bool m = (lc[j] == labr);
                rD += e; if (m) rN += e;
                colD[j] += e; if (m) colN[j] += e;
            }
            // row sums: reduce across the 16 column-lanes of this quad
#pragma unroll
            for (int msk = 1; msk <= 8; msk <<= 1) {
                rD += __shfl_xor(rD, msk, 64);
                rN += __shfl_xor(rN, msk, 64);
            }
            if (l15 == 0) {
                atomicAdd(&den[grow], rD);
                atomicAdd(&nom[grow], rN);
            }
        }
    }
    if (offd) {
        // symmetric counterpart: column sums scattered as row sums of (c,r)
#pragma unroll
        for (int j = 0; j < 4; ++j) {
            float cd = colD[j], cn = colN[j];
            cd += __shfl_xor(cd, 16, 64); cn += __shfl_xor(cn, 16, 64);
            cd += __shfl_xor(cd, 32, 64); cn += __shfl_xor(cn, 32, 64);
            if (quad == 0) {
                atomicAdd(&den[gcol[j]], cd);
                atomicAdd(&nom[gcol[j]], cn);
            }
        }
    }
}

__global__ __launch_bounds__(256) void finalize_kernel(
    const float* __restrict__ nom, const float* __restrict__ den,
    float* __restrict__ out) {
    int idx = blockIdx.x * 256 + threadIdx.x;   // 32 blocks x 256
    int t = threadIdx.x;
    float s = 0.f;
    if (idx < N2) s = logf(den[idx]) - logf(nom[idx]);   // -log(nom/den)
#pragma unroll
    for (int m = 1; m <= 32; m <<= 1) s += __shfl_xor(s, m, 64);
    __shared__ float red[4];
    if ((t & 63) == 0) red[t >> 6] = s;
    __syncthreads();
    if (t == 0)
        atomicAdd(out, (red[0] + red[1] + red[2] + red[3]) / (float)N2);
}

extern "C" void kernel_launch(void* const* d_in, const int* in_sizes, int n_in,
                              void* d_out, int out_size, void* d_ws, size_t ws_size,
                              hipStream_t stream) {
    const float* emb_i = (const float*)d_in[0];
    const float* emb_j = (const float*)d_in[1];
    const int* labels  = (const int*)d_in[2];
    float* out = (float*)d_out;

    char* ws = (char*)d_ws;
    u8* reps   = (u8*)ws;                                   // 8192*1024 = 8 MB
    float* nom = (float*)(ws + (size_t)N2 * DK);            // 32 KB
    float* den = nom + N2;                                  // 32 KB

    normalize_kernel<<<N2, 256, 0, stream>>>(emb_i, emb_j, reps, nom, out);
    gemm_loss_kernel<<<NBLK, 256, 0, stream>>>(reps, labels, nom, den);
    finalize_kernel<<<(N2 + 255) / 256, 256, 0, stream>>>(nom, den, out);
}